// Round 9
// baseline (507.372 us; speedup 1.0000x reference)
//
#include <hip/hip_runtime.h>
#include <math.h>

#define HID    128
#define IN_CH  271
#define SEQ    281
#define NCLS   1854
#define BATCH  256
#define M_TOT  (SEQ * BATCH)          // 71936 = 562 * 128
#define KPAD0  288                    // 271 padded to 9*32

typedef __attribute__((ext_vector_type(8))) short short8;
typedef __attribute__((ext_vector_type(4))) float floatx4;

#define MFMA16(acc, a, b) acc = __builtin_amdgcn_mfma_f32_16x16x32_bf16((a), (b), (acc), 0, 0, 0)

__device__ __forceinline__ unsigned short f2bf(float f) {
    union { float f; unsigned u; } v; v.f = f;
    unsigned u = v.u;
    u += 0x7FFF + ((u >> 16) & 1);        // RNE
    return (unsigned short)(u >> 16);
}
// single-instruction bf16 convert (RNE, bit-identical to f2bf for finite vals)
__device__ __forceinline__ unsigned short cvt_bf16(float f) {
    unsigned r;
    asm("v_cvt_pk_bf16_f32 %0, %1, %1" : "=v"(r) : "v"(f));
    return (unsigned short)r;
}
__device__ __forceinline__ float fast_rcp(float x) {
    float r;
    asm("v_rcp_f32 %0, %1" : "=v"(r) : "v"(x));
    return r;
}
__device__ __forceinline__ float fast_sigmoid(float s) {
    return fast_rcp(1.f + __expf(-s));
}
// tanh(x) = 2/(1+e^{-2x}) - 1 ; exp limits give exactly -1/+1, branch-free
__device__ __forceinline__ float fast_tanh(float s) {
    float e = __expf(-2.f * s);
    return __builtin_fmaf(2.f, fast_rcp(1.f + e), -1.f);
}
// LDS-only barrier: waits ds-ops but does NOT drain vmcnt.
__device__ __forceinline__ void sync_lds() {
    asm volatile("s_waitcnt lgkmcnt(0)\n\ts_barrier" ::: "memory");
}

// ---------------------------------------------------------------------------
// 4-row swizzled LDS h-tile (R2-verified: SQ_LDS_BANK_CONFLICT = 0):
//   element (row, k) at  row*128 + (((k>>3) ^ (2*row)) << 3) + (k&7)
// ---------------------------------------------------------------------------
__device__ __forceinline__ short8 ldsA_r4(const unsigned short* base, int l15, int kk, int quad) {
    const int row4  = l15 >> 2;
    const int chunk = (4 * kk + quad) ^ (row4 << 1);
    return *(const short8*)(base + row4 * 128 + (chunk << 3));
}
__device__ __forceinline__ int sw_idx4(int row, int c) {
    return row * 128 + ((((c >> 3) ^ (row << 1)) << 3) | (c & 7));
}

// ---------------------------------------------------------------------------
// Transpose+convert X: X[b][k][t] fp32 -> Abf[(t*256 + b)*288 + k] bf16.
// R9: Abf layout changed [b][t][k] -> [t][b][k].  Storage row = t*256+b =
// the gemm's logical row m', so gemm A-tiles are 73.7 KB CONTIGUOUS panels
// (R8's layout put consecutive tile rows 162 KB apart -> 64B-granule scatter
// ~ the inferred ~87 us).  xt write granularity: 576 B/row, coalesced.
// ---------------------------------------------------------------------------
__global__ __launch_bounds__(256) void xt_kernel(
    const float* __restrict__ X, unsigned short* __restrict__ Abf)
{
    const int tb = blockIdx.x;            // 0..4, t-tile of 64
    const int b  = blockIdx.y;
    const int tid = threadIdx.x;
    const int t0 = tb * 64;
    const float* __restrict__ Xb = X + (size_t)b * (IN_CH * SEQ);

    __shared__ float Xl[32][65];

    for (int kc = 0; kc < KPAD0 / 32; ++kc) {
#pragma unroll
        for (int r = 0; r < 8; ++r) {
            int e = tid + 256 * r;
            int kk = e >> 6, tt = e & 63;
            int k = kc * 32 + kk, t = t0 + tt;
            Xl[kk][tt] = (k < IN_CH && t < SEQ) ? Xb[k * SEQ + t] : 0.f;
        }
        __syncthreads();
        {
            int tt = tid >> 2, part = tid & 3;
            int t = t0 + tt;
            if (t < SEQ) {
                union { unsigned short s[8]; uint4 v; } u;
#pragma unroll
                for (int i = 0; i < 8; ++i) u.s[i] = f2bf(Xl[part * 8 + i][tt]);
                *(uint4*)(Abf + ((size_t)t * BATCH + b) * KPAD0 + kc * 32 + part * 8) = u.v;
            }
        }
        __syncthreads();
    }
}

// ---------------------------------------------------------------------------
// Weight transpose+convert. grid (12, 32), blockIdx.y = n-slice of 4.
// blk 0..2 : Wt0 [n][288]        = W0g[k][n], k<271, zero-padded (gemm B)
// blk 3..5 : Wh0 [g*128+n][128]  = W0g[271+k][n]     (gru, layer0 h-part)
// blk 6..8 : Wx1 [g*128+n][128]  = W1g[k][n]         (gru, layer1 x-part)
// blk 9..11: Wh1 [g*128+n][128]  = W1g[128+k][n]     (gru, layer1 h-part)
// ---------------------------------------------------------------------------
__global__ __launch_bounds__(256) void wt_kernel(
    const float* __restrict__ Wr0, const float* __restrict__ Wu0, const float* __restrict__ Wo0,
    const float* __restrict__ Wr1, const float* __restrict__ Wu1, const float* __restrict__ Wo1,
    unsigned short* __restrict__ Wt0, unsigned short* __restrict__ Wh0,
    unsigned short* __restrict__ Wx1, unsigned short* __restrict__ Wh1)
{
    const int blk  = blockIdx.x;
    const int kind = blk / 3, g = blk % 3;
    const int tid  = threadIdx.x;
    const int n0   = blockIdx.y * 4;

    const float* __restrict__ W =
        (kind <= 1) ? ((g == 0) ? Wr0 : (g == 1) ? Wu0 : Wo0)
                    : ((g == 0) ? Wr1 : (g == 1) ? Wu1 : Wo1);

    if (kind == 0) {
        unsigned short* __restrict__ out = Wt0 + (size_t)g * HID * KPAD0;
        for (int n = n0; n < n0 + 4; ++n)
            for (int k = tid; k < KPAD0; k += 256) {
                float v = (k < IN_CH) ? W[(size_t)k * HID + n] : 0.f;
                out[(size_t)n * KPAD0 + k] = f2bf(v);
            }
    } else {
        const int rbase = (kind == 1) ? IN_CH : (kind == 2) ? 0 : HID;
        unsigned short* __restrict__ out =
            ((kind == 1) ? Wh0 : (kind == 2) ? Wx1 : Wh1) + (size_t)g * HID * HID;
        for (int n = n0; n < n0 + 4; ++n)
            for (int k = tid; k < HID; k += 256)
                out[(size_t)n * HID + k] = f2bf(W[(size_t)(rbase + k) * HID + n]);
    }
}

// ---------------------------------------------------------------------------
// bf16 MFMA GEMM (layer-0 x-contributions only) — R4-proven structure.
// R9: with Abf[m'][k] (m' = t*256+b), A-tile addressing is simply
// (m0 + r)*KPAD0: each block streams a contiguous 73.7 KB panel (read 3x
// across the gate grid; 2nd/3rd hit L3).  MFMA core/epilogue = R8 verbatim.
// Output layout [b>>2][t][b&3][chan] (gru's proven read pattern).
// ---------------------------------------------------------------------------
__global__ __launch_bounds__(256) void gemm_xg(
    const unsigned short* __restrict__ A,
    const unsigned short* __restrict__ Wt,
    float* __restrict__ XG)
{
    const int g = blockIdx.y;
    const unsigned short* __restrict__ B = Wt + (size_t)g * HID * KPAD0;

    __shared__ unsigned short As[128 * 40];
    __shared__ unsigned short Bs[128 * 40];

    const int tid   = threadIdx.x;
    const int lane  = tid & 63;
    const int wave  = tid >> 6;
    const int l15   = lane & 15;
    const int quad  = lane >> 4;
    const int mhalf = wave >> 1;
    const int nhalf = wave & 1;
    const int m0    = blockIdx.x * 128;
    const int tt    = m0 >> 8;
    const int b0m   = m0 & 255;

    floatx4 acc[4][4];
#pragma unroll
    for (int im = 0; im < 4; ++im)
#pragma unroll
        for (int in = 0; in < 4; ++in) acc[im][in] = (floatx4)0.f;

    const int r0 = tid >> 2, p0 = tid & 3;
    const int r1 = (tid + 256) >> 2, p1 = tid & 3;

    for (int kt = 0; kt < KPAD0 / 32; ++kt) {
        if (kt) __syncthreads();
        const int kb = kt * 32;
        uint4 va0 = *(const uint4*)(A + (size_t)(m0 + r0) * KPAD0 + kb + p0 * 8);
        uint4 va1 = *(const uint4*)(A + (size_t)(m0 + r1) * KPAD0 + kb + p1 * 8);
        uint4 vb0 = *(const uint4*)(B + (size_t)r0 * KPAD0 + kb + p0 * 8);
        uint4 vb1 = *(const uint4*)(B + (size_t)r1 * KPAD0 + kb + p1 * 8);
        *(uint4*)(As + r0 * 40 + p0 * 8) = va0;
        *(uint4*)(As + r1 * 40 + p1 * 8) = va1;
        *(uint4*)(Bs + r0 * 40 + p0 * 8) = vb0;
        *(uint4*)(Bs + r1 * 40 + p1 * 8) = vb1;
        __syncthreads();

        short8 af[4], bf[4];
#pragma unroll
        for (int im = 0; im < 4; ++im)
            af[im] = *(const short8*)(As + (mhalf * 64 + im * 16 + l15) * 40 + quad * 8);
#pragma unroll
        for (int in = 0; in < 4; ++in)
            bf[in] = *(const short8*)(Bs + (nhalf * 64 + in * 16 + l15) * 40 + quad * 8);
#pragma unroll
        for (int im = 0; im < 4; ++im)
#pragma unroll
            for (int in = 0; in < 4; ++in)
                MFMA16(acc[im][in], af[im], bf[in]);
    }

    // epilogue: XG[(bb>>2)][tt][j][g*128+n] = acc[im][in][j]  (raw, no bias)
#pragma unroll
    for (int im = 0; im < 4; ++im) {
        const int bb = b0m + mhalf * 64 + im * 16 + quad * 4;   // 4-aligned
        const size_t rbase = ((size_t)(bb >> 2) * SEQ + tt) * 1536;
#pragma unroll
        for (int in = 0; in < 4; ++in) {
            const int chan = g * HID + nhalf * 64 + in * 16 + l15;
            float* dst = XG + rbase + chan;
#pragma unroll
            for (int j = 0; j < 4; ++j)
                dst[j * 384] = acc[im][in][j];
        }
    }
}

// ---------------------------------------------------------------------------
// FUSED 2-layer GRU — 64 blocks x 4 batch rows, skewed 2-phase pipeline.
// R7/R8-measured: 250 us, VGPR 116, conflicts 0 — best gru; UNCHANGED.
// At structural floor for bf16 16x16x32: per-CU 288 MFMA/iter (invariant in
// rows/block since rows*blocks = BATCH) + 2-barrier round-trip latency.
// Layer-0 bias folded here.
// ---------------------------------------------------------------------------
__global__ __launch_bounds__(512, 1) void gru_fused(
    const unsigned short* __restrict__ Wh0,
    const unsigned short* __restrict__ Wx1,
    const unsigned short* __restrict__ Wh1,
    const float* __restrict__ XG,
    const float* __restrict__ br0, const float* __restrict__ bu0, const float* __restrict__ bo0,
    const float* __restrict__ br1, const float* __restrict__ bu1, const float* __restrict__ bo1,
    float* __restrict__ H1fin)
{
    const int b0   = blockIdx.x * 4;
    const int tid  = threadIdx.x;
    const int w    = tid >> 6;        // 0..7
    const int lane = tid & 63;
    const int l15  = lane & 15;
    const int quad = lane >> 4;       // this lane's batch row 0..3
    const int c    = w * 16 + l15;    // this lane's column 0..127

    __shared__ __attribute__((aligned(16))) unsigned short Hbf0[4 * 128];
    __shared__ __attribute__((aligned(16))) unsigned short Rbf0[4 * 128];
    __shared__ __attribute__((aligned(16))) unsigned short Hbf1[4 * 128];
    __shared__ __attribute__((aligned(16))) unsigned short Rbf1[4 * 128];

    // hoisted weight B-fragments: 9 (layer,gate) tiles x 4 k-steps
    short8 B0r[4], B0u[4], B0o[4], Bxr[4], Bxu[4], Bxo[4], B1r[4], B1u[4], B1o[4];
#pragma unroll
    for (int kk = 0; kk < 4; ++kk) {
        const size_t off = (size_t)c * HID + kk * 32 + quad * 8;
        B0r[kk] = *(const short8*)(Wh0 + off);
        B0u[kk] = *(const short8*)(Wh0 + (size_t)128 * HID + off);
        B0o[kk] = *(const short8*)(Wh0 + (size_t)256 * HID + off);
        Bxr[kk] = *(const short8*)(Wx1 + off);
        Bxu[kk] = *(const short8*)(Wx1 + (size_t)128 * HID + off);
        Bxo[kk] = *(const short8*)(Wx1 + (size_t)256 * HID + off);
        B1r[kk] = *(const short8*)(Wh1 + off);
        B1u[kk] = *(const short8*)(Wh1 + (size_t)128 * HID + off);
        B1o[kk] = *(const short8*)(Wh1 + (size_t)256 * HID + off);
    }

    for (int idx = tid; idx < 4 * 128; idx += 512) {
        Hbf0[idx] = 0; Rbf0[idx] = 0; Hbf1[idx] = 0; Rbf1[idx] = 0;
    }

    float h0s = 0.f, h1s = 0.f, ug0s = 0.f, ug1s = 0.f;

    const float b0r_c = br0[c], b0u_c = bu0[c], b0o_c = bo0[c];
    const float br1c = br1[c], bu1c = bu1[c], bo1c = bo1[c];

    // swizzled write index for this lane's single cell (row=quad, col=c)
    const int swi = sw_idx4(quad, c);

    // XG [gb][t][r=quad][chan]: lane reads chan=c (+128,+256)
    const float* xgp = XG + (size_t)blockIdx.x * SEQ * 1536 + quad * 384 + c;
    float xr = xgp[0];
    float xu = xgp[128];
    float xo = xgp[256];
    xgp += 1536;
    __syncthreads();

    for (int i = 0; i <= SEQ; ++i) {
        const bool l0 = (i < SEQ);     // layer 0 computes step i
        const bool l1 = (i > 0);       // layer 1 computes step i-1

        // prefetch xg(i+1) — lands during this step's compute
        float nr, nu, no;
        const bool pf = (i + 1 < SEQ);
        if (pf) {
            nr = xgp[0];
            nu = xgp[128];
            no = xgp[256];
            xgp += 1536;
        }

        // ---- Phase A: single read of h0(i-1)/h1(i-2); all r,u gates + L1 o-x part
        short8 a0[4], a1[4];
#pragma unroll
        for (int kk = 0; kk < 4; ++kk) {
            a0[kk] = ldsA_r4(Hbf0, l15, kk, quad);
            a1[kk] = ldsA_r4(Hbf1, l15, kk, quad);
        }
        floatx4 ar = (floatx4)0.f, au = (floatx4)0.f;
        floatx4 a1r = (floatx4)0.f, a1u = (floatx4)0.f, axo = (floatx4)0.f;
        if (l0) {
#pragma unroll
            for (int kk = 0; kk < 4; ++kk) {
                MFMA16(ar, a0[kk], B0r[kk]);
                MFMA16(au, a0[kk], B0u[kk]);
            }
        }
        if (l1) {
#pragma unroll
            for (int kk = 0; kk < 4; ++kk) {
                MFMA16(a1r, a0[kk], Bxr[kk]);
                MFMA16(a1u, a0[kk], Bxu[kk]);
                MFMA16(axo, a0[kk], Bxo[kk]);
                MFMA16(a1r, a1[kk], B1r[kk]);
                MFMA16(a1u, a1[kk], B1u[kk]);
            }
        }
        if (l0) {
            float rg = fast_sigmoid(ar[0] + xr + b0r_c);
            ug0s = fast_sigmoid(au[0] + xu + b0u_c);
            Rbf0[swi] = cvt_bf16(rg * h0s);
        }
        if (l1) {
            float rg1 = fast_sigmoid(a1r[0] + br1c);
            ug1s = fast_sigmoid(a1u[0] + bu1c);
            Rbf1[swi] = cvt_bf16(rg1 * h1s);
        }
        sync_lds();

        // ---- Phase B: both o gates + both h updates
        floatx4 ao = (floatx4)0.f;
        if (l0) {
#pragma unroll
            for (int kk = 0; kk < 4; ++kk)
                MFMA16(ao, ldsA_r4(Rbf0, l15, kk, quad), B0o[kk]);
        }
        if (l1) {
#pragma unroll
            for (int kk = 0; kk < 4; ++kk)
                MFMA16(axo, ldsA_r4(Rbf1, l15, kk, quad), B1o[kk]);
        }
        if (l0) {
            float og = fast_tanh(ao[0] + xo + b0o_c);
            h0s = h0s + ug0s * (og - h0s);
            Hbf0[swi] = cvt_bf16(h0s);
        }
        if (l1) {
            float og1 = fast_tanh(axo[0] + bo1c);
            h1s = h1s + ug1s * (og1 - h1s);
            Hbf1[swi] = cvt_bf16(h1s);
        }
        if (pf) { xr = nr; xu = nu; xo = no; }
        sync_lds();
    }

    H1fin[(size_t)(b0 + quad) * HID + c] = h1s;
}

// ---------------------------------------------------------------------------
// Classifier: out[b][c] = bfc[c] + sum_k H1[b][k] * Wfc[k][c]
// ---------------------------------------------------------------------------
__global__ __launch_bounds__(256) void cls_kernel(
    const float* __restrict__ H1, const float* __restrict__ Wfc,
    const float* __restrict__ bfc, float* __restrict__ out)
{
    const int b = blockIdx.x;
    const int tid = threadIdx.x;
    __shared__ float h[HID];
    if (tid < HID) h[tid] = H1[(size_t)b * HID + tid];
    __syncthreads();
    for (int c = tid; c < NCLS; c += 256) {
        float a = bfc[c];
#pragma unroll 8
        for (int k = 0; k < HID; ++k)
            a += h[k] * Wfc[(size_t)k * NCLS + c];
        out[(size_t)b * NCLS + c] = a;
    }
}

// ---------------------------------------------------------------------------
extern "C" void kernel_launch(void* const* d_in, const int* in_sizes, int n_in,
                              void* d_out, int out_size, void* d_ws, size_t ws_size,
                              hipStream_t stream)
{
    const float* X   = (const float*)d_in[0];
    const float* Wr0 = (const float*)d_in[1];
    const float* br0 = (const float*)d_in[2];
    const float* Wu0 = (const float*)d_in[3];
    const float* bu0 = (const float*)d_in[4];
    const float* Wo0 = (const float*)d_in[5];
    const float* bo0 = (const float*)d_in[6];
    const float* Wr1 = (const float*)d_in[7];
    const float* br1 = (const float*)d_in[8];
    const float* Wu1 = (const float*)d_in[9];
    const float* bu1 = (const float*)d_in[10];
    const float* Wo1 = (const float*)d_in[11];
    const float* bo1 = (const float*)d_in[12];
    const float* Wfc = (const float*)d_in[13];
    const float* bfc = (const float*)d_in[14];
    float* out = (float*)d_out;

    // workspace:
    //   XG  fp32 [64][281][4][384]  110,493,696 B  ([b>>2][t][b&3][chan])
    //   Abf bf16 [M_TOT*288]         41,435,136 B  ([t][b][k]; H1fin aliases)
    //   Wt0 bf16 [3*128*288]            221,184 B
    //   Wh0/Wx1/Wh1 bf16 [384*128]       98,304 B each
    char* ws = (char*)d_ws;
    float*          XG    = (float*)ws;
    unsigned short* Abf   = (unsigned short*)(ws + (size_t)M_TOT * 384 * 4);
    float*          H1fin = (float*)Abf;        // alias: Abf dead after gemm_xg
    unsigned short* Wt0   = (unsigned short*)(ws + (size_t)M_TOT * 384 * 4 + (size_t)M_TOT * KPAD0 * 2);
    unsigned short* Wh0   = Wt0 + (size_t)3 * HID * KPAD0;
    unsigned short* Wx1   = Wh0 + (size_t)384 * HID;
    unsigned short* Wh1   = Wx1 + (size_t)384 * HID;

    wt_kernel<<<dim3(12, 32), 256, 0, stream>>>(Wr0, Wu0, Wo0, Wr1, Wu1, Wo1,
                                                Wt0, Wh0, Wx1, Wh1);
    xt_kernel<<<dim3(5, BATCH), 256, 0, stream>>>(X, Abf);
    gemm_xg  <<<dim3(M_TOT / 128, 3), 256, 0, stream>>>(Abf, Wt0, XG);
    gru_fused<<<dim3(64), 512, 0, stream>>>(Wh0, Wx1, Wh1, XG,
                                            br0, bu0, bo0, br1, bu1, bo1, H1fin);
    cls_kernel<<<dim3(BATCH), 256, 0, stream>>>(H1fin, Wfc, bfc, out);
}

// Round 10
// 471.245 us; speedup vs baseline: 1.0767x; 1.0767x over previous
//
#include <hip/hip_runtime.h>
#include <math.h>

#define HID    128
#define IN_CH  271
#define SEQ    281
#define NCLS   1854
#define BATCH  256
#define M_TOT  (SEQ * BATCH)          // 71936 = 562 * 128
#define KPAD0  288                    // 271 padded to 9*32

typedef __attribute__((ext_vector_type(8))) short short8;
typedef __attribute__((ext_vector_type(4))) float floatx4;

#define MFMA16(acc, a, b) acc = __builtin_amdgcn_mfma_f32_16x16x32_bf16((a), (b), (acc), 0, 0, 0)

__device__ __forceinline__ unsigned short f2bf(float f) {
    union { float f; unsigned u; } v; v.f = f;
    unsigned u = v.u;
    u += 0x7FFF + ((u >> 16) & 1);        // RNE
    return (unsigned short)(u >> 16);
}
// single-instruction bf16 convert (RNE, bit-identical to f2bf for finite vals)
__device__ __forceinline__ unsigned short cvt_bf16(float f) {
    unsigned r;
    asm("v_cvt_pk_bf16_f32 %0, %1, %1" : "=v"(r) : "v"(f));
    return (unsigned short)r;
}
__device__ __forceinline__ float fast_rcp(float x) {
    float r;
    asm("v_rcp_f32 %0, %1" : "=v"(r) : "v"(x));
    return r;
}
__device__ __forceinline__ float fast_sigmoid(float s) {
    return fast_rcp(1.f + __expf(-s));
}
// tanh(x) = 2/(1+e^{-2x}) - 1 ; exp limits give exactly -1/+1, branch-free
__device__ __forceinline__ float fast_tanh(float s) {
    float e = __expf(-2.f * s);
    return __builtin_fmaf(2.f, fast_rcp(1.f + e), -1.f);
}
// LDS-only barrier: waits ds-ops but does NOT drain vmcnt.
__device__ __forceinline__ void sync_lds() {
    asm volatile("s_waitcnt lgkmcnt(0)\n\ts_barrier" ::: "memory");
}

// ---------------------------------------------------------------------------
// 4-row swizzled LDS h-tile (R2-verified: SQ_LDS_BANK_CONFLICT = 0):
//   element (row, k) at  row*128 + (((k>>3) ^ (2*row)) << 3) + (k&7)
// ---------------------------------------------------------------------------
__device__ __forceinline__ short8 ldsA_r4(const unsigned short* base, int l15, int kk, int quad) {
    const int row4  = l15 >> 2;
    const int chunk = (4 * kk + quad) ^ (row4 << 1);
    return *(const short8*)(base + row4 * 128 + (chunk << 3));
}
__device__ __forceinline__ int sw_idx4(int row, int c) {
    return row * 128 + ((((c >> 3) ^ (row << 1)) << 3) | (c & 7));
}

// ---------------------------------------------------------------------------
// PREP (R10: wt + xt merged; one dispatch instead of two).
// blocks 0..383   : weight transpose+convert (bid/32 = blk 0..11, bid%32 = n-slice)
//   blk 0..2 : Wt0 [n][288]        = W0g[k][n], k<271, zero-padded (gemm B)
//   blk 3..5 : Wh0 [g*128+n][128]  = W0g[271+k][n]
//   blk 6..8 : Wx1 [g*128+n][128]  = W1g[k][n]
//   blk 9..11: Wh1 [g*128+n][128]  = W1g[128+k][n]
// blocks 384..1663: X transpose+convert -> Abf[(t*256+b)*288 + k] bf16
//   u = bid-384: tb = u%5 (t-tile of 64), b = u/5
// ---------------------------------------------------------------------------
__global__ __launch_bounds__(256) void prep_kernel(
    const float* __restrict__ X,
    const float* __restrict__ Wr0, const float* __restrict__ Wu0, const float* __restrict__ Wo0,
    const float* __restrict__ Wr1, const float* __restrict__ Wu1, const float* __restrict__ Wo1,
    unsigned short* __restrict__ Abf,
    unsigned short* __restrict__ Wt0, unsigned short* __restrict__ Wh0,
    unsigned short* __restrict__ Wx1, unsigned short* __restrict__ Wh1)
{
    __shared__ float Xl[32][65];
    const int bid = blockIdx.x;
    const int tid = threadIdx.x;

    if (bid < 384) {
        const int blk  = bid >> 5;          // 0..11
        const int kind = blk / 3, g = blk % 3;
        const int n0   = (bid & 31) * 4;

        const float* __restrict__ W =
            (kind <= 1) ? ((g == 0) ? Wr0 : (g == 1) ? Wu0 : Wo0)
                        : ((g == 0) ? Wr1 : (g == 1) ? Wu1 : Wo1);

        if (kind == 0) {
            unsigned short* __restrict__ out = Wt0 + (size_t)g * HID * KPAD0;
            for (int n = n0; n < n0 + 4; ++n)
                for (int k = tid; k < KPAD0; k += 256) {
                    float v = (k < IN_CH) ? W[(size_t)k * HID + n] : 0.f;
                    out[(size_t)n * KPAD0 + k] = f2bf(v);
                }
        } else {
            const int rbase = (kind == 1) ? IN_CH : (kind == 2) ? 0 : HID;
            unsigned short* __restrict__ out =
                ((kind == 1) ? Wh0 : (kind == 2) ? Wx1 : Wh1) + (size_t)g * HID * HID;
            for (int n = n0; n < n0 + 4; ++n)
                for (int k = tid; k < HID; k += 256)
                    out[(size_t)n * HID + k] = f2bf(W[(size_t)(rbase + k) * HID + n]);
        }
    } else {
        const int u  = bid - 384;
        const int tb = u % 5, b = u / 5;
        const int t0 = tb * 64;
        const float* __restrict__ Xb = X + (size_t)b * (IN_CH * SEQ);

        for (int kc = 0; kc < KPAD0 / 32; ++kc) {
#pragma unroll
            for (int r = 0; r < 8; ++r) {
                int e = tid + 256 * r;
                int kk = e >> 6, tt = e & 63;
                int k = kc * 32 + kk, t = t0 + tt;
                Xl[kk][tt] = (k < IN_CH && t < SEQ) ? Xb[k * SEQ + t] : 0.f;
            }
            __syncthreads();
            {
                int tt = tid >> 2, part = tid & 3;
                int t = t0 + tt;
                if (t < SEQ) {
                    union { unsigned short s[8]; uint4 v; } uu;
#pragma unroll
                    for (int i = 0; i < 8; ++i) uu.s[i] = f2bf(Xl[part * 8 + i][tt]);
                    *(uint4*)(Abf + ((size_t)t * BATCH + b) * KPAD0 + kc * 32 + part * 8) = uu.v;
                }
            }
            __syncthreads();
        }
    }
}

// ---------------------------------------------------------------------------
// bf16 MFMA GEMM (layer-0 x-contributions only) — R9 verbatim.
// Abf[m'][k] (m' = t*256+b): A-tile = contiguous 73.7 KB panel.
// Output layout [b>>2][t][b&3][chan] (gru's proven read pattern).
// ---------------------------------------------------------------------------
__global__ __launch_bounds__(256) void gemm_xg(
    const unsigned short* __restrict__ A,
    const unsigned short* __restrict__ Wt,
    float* __restrict__ XG)
{
    const int g = blockIdx.y;
    const unsigned short* __restrict__ B = Wt + (size_t)g * HID * KPAD0;

    __shared__ unsigned short As[128 * 40];
    __shared__ unsigned short Bs[128 * 40];

    const int tid   = threadIdx.x;
    const int lane  = tid & 63;
    const int wave  = tid >> 6;
    const int l15   = lane & 15;
    const int quad  = lane >> 4;
    const int mhalf = wave >> 1;
    const int nhalf = wave & 1;
    const int m0    = blockIdx.x * 128;
    const int tt    = m0 >> 8;
    const int b0m   = m0 & 255;

    floatx4 acc[4][4];
#pragma unroll
    for (int im = 0; im < 4; ++im)
#pragma unroll
        for (int in = 0; in < 4; ++in) acc[im][in] = (floatx4)0.f;

    const int r0 = tid >> 2, p0 = tid & 3;
    const int r1 = (tid + 256) >> 2, p1 = tid & 3;

    for (int kt = 0; kt < KPAD0 / 32; ++kt) {
        if (kt) __syncthreads();
        const int kb = kt * 32;
        uint4 va0 = *(const uint4*)(A + (size_t)(m0 + r0) * KPAD0 + kb + p0 * 8);
        uint4 va1 = *(const uint4*)(A + (size_t)(m0 + r1) * KPAD0 + kb + p1 * 8);
        uint4 vb0 = *(const uint4*)(B + (size_t)r0 * KPAD0 + kb + p0 * 8);
        uint4 vb1 = *(const uint4*)(B + (size_t)r1 * KPAD0 + kb + p1 * 8);
        *(uint4*)(As + r0 * 40 + p0 * 8) = va0;
        *(uint4*)(As + r1 * 40 + p1 * 8) = va1;
        *(uint4*)(Bs + r0 * 40 + p0 * 8) = vb0;
        *(uint4*)(Bs + r1 * 40 + p1 * 8) = vb1;
        __syncthreads();

        short8 af[4], bf[4];
#pragma unroll
        for (int im = 0; im < 4; ++im)
            af[im] = *(const short8*)(As + (mhalf * 64 + im * 16 + l15) * 40 + quad * 8);
#pragma unroll
        for (int in = 0; in < 4; ++in)
            bf[in] = *(const short8*)(Bs + (nhalf * 64 + in * 16 + l15) * 40 + quad * 8);
#pragma unroll
        for (int im = 0; im < 4; ++im)
#pragma unroll
            for (int in = 0; in < 4; ++in)
                MFMA16(acc[im][in], af[im], bf[in]);
    }

    // epilogue: XG[(bb>>2)][tt][j][g*128+n] = acc[im][in][j]  (raw, no bias)
#pragma unroll
    for (int im = 0; im < 4; ++im) {
        const int bb = b0m + mhalf * 64 + im * 16 + quad * 4;   // 4-aligned
        const size_t rbase = ((size_t)(bb >> 2) * SEQ + tt) * 1536;
#pragma unroll
        for (int in = 0; in < 4; ++in) {
            const int chan = g * HID + nhalf * 64 + in * 16 + l15;
            float* dst = XG + rbase + chan;
#pragma unroll
            for (int j = 0; j < 4; ++j)
                dst[j * 384] = acc[im][in][j];
        }
    }
}

// ---------------------------------------------------------------------------
// FUSED 2-layer GRU + CLASSIFIER TAIL — 64 blocks x 4 batch rows.
// Loop body = R7/R8/R9-measured 250 us (VGPR 116, conflicts 0), UNCHANGED.
// R10: classifier fused as a tail (h1 staged to 2 KB LDS; same fp32 k-order
// fma as the old cls kernel) — deletes the cls dispatch, its launch gap,
// and the H1fin global round trip.  Wfc (949 KB) L2/L3-cached across blocks.
// ---------------------------------------------------------------------------
__global__ __launch_bounds__(512, 1) void gru_fused(
    const unsigned short* __restrict__ Wh0,
    const unsigned short* __restrict__ Wx1,
    const unsigned short* __restrict__ Wh1,
    const float* __restrict__ XG,
    const float* __restrict__ br0, const float* __restrict__ bu0, const float* __restrict__ bo0,
    const float* __restrict__ br1, const float* __restrict__ bu1, const float* __restrict__ bo1,
    const float* __restrict__ Wfc, const float* __restrict__ bfc,
    float* __restrict__ out)
{
    const int b0   = blockIdx.x * 4;
    const int tid  = threadIdx.x;
    const int w    = tid >> 6;        // 0..7
    const int lane = tid & 63;
    const int l15  = lane & 15;
    const int quad = lane >> 4;       // this lane's batch row 0..3
    const int c    = w * 16 + l15;    // this lane's column 0..127

    __shared__ __attribute__((aligned(16))) unsigned short Hbf0[4 * 128];
    __shared__ __attribute__((aligned(16))) unsigned short Rbf0[4 * 128];
    __shared__ __attribute__((aligned(16))) unsigned short Hbf1[4 * 128];
    __shared__ __attribute__((aligned(16))) unsigned short Rbf1[4 * 128];
    __shared__ float Hf[4][HID];      // cls tail staging

    // hoisted weight B-fragments: 9 (layer,gate) tiles x 4 k-steps
    short8 B0r[4], B0u[4], B0o[4], Bxr[4], Bxu[4], Bxo[4], B1r[4], B1u[4], B1o[4];
#pragma unroll
    for (int kk = 0; kk < 4; ++kk) {
        const size_t off = (size_t)c * HID + kk * 32 + quad * 8;
        B0r[kk] = *(const short8*)(Wh0 + off);
        B0u[kk] = *(const short8*)(Wh0 + (size_t)128 * HID + off);
        B0o[kk] = *(const short8*)(Wh0 + (size_t)256 * HID + off);
        Bxr[kk] = *(const short8*)(Wx1 + off);
        Bxu[kk] = *(const short8*)(Wx1 + (size_t)128 * HID + off);
        Bxo[kk] = *(const short8*)(Wx1 + (size_t)256 * HID + off);
        B1r[kk] = *(const short8*)(Wh1 + off);
        B1u[kk] = *(const short8*)(Wh1 + (size_t)128 * HID + off);
        B1o[kk] = *(const short8*)(Wh1 + (size_t)256 * HID + off);
    }

    for (int idx = tid; idx < 4 * 128; idx += 512) {
        Hbf0[idx] = 0; Rbf0[idx] = 0; Hbf1[idx] = 0; Rbf1[idx] = 0;
    }

    float h0s = 0.f, h1s = 0.f, ug0s = 0.f, ug1s = 0.f;

    const float b0r_c = br0[c], b0u_c = bu0[c], b0o_c = bo0[c];
    const float br1c = br1[c], bu1c = bu1[c], bo1c = bo1[c];

    // swizzled write index for this lane's single cell (row=quad, col=c)
    const int swi = sw_idx4(quad, c);

    // XG [gb][t][r=quad][chan]: lane reads chan=c (+128,+256)
    const float* xgp = XG + (size_t)blockIdx.x * SEQ * 1536 + quad * 384 + c;
    float xr = xgp[0];
    float xu = xgp[128];
    float xo = xgp[256];
    xgp += 1536;
    __syncthreads();

    for (int i = 0; i <= SEQ; ++i) {
        const bool l0 = (i < SEQ);     // layer 0 computes step i
        const bool l1 = (i > 0);       // layer 1 computes step i-1

        // prefetch xg(i+1) — lands during this step's compute
        float nr, nu, no;
        const bool pf = (i + 1 < SEQ);
        if (pf) {
            nr = xgp[0];
            nu = xgp[128];
            no = xgp[256];
            xgp += 1536;
        }

        // ---- Phase A: single read of h0(i-1)/h1(i-2); all r,u gates + L1 o-x part
        short8 a0[4], a1[4];
#pragma unroll
        for (int kk = 0; kk < 4; ++kk) {
            a0[kk] = ldsA_r4(Hbf0, l15, kk, quad);
            a1[kk] = ldsA_r4(Hbf1, l15, kk, quad);
        }
        floatx4 ar = (floatx4)0.f, au = (floatx4)0.f;
        floatx4 a1r = (floatx4)0.f, a1u = (floatx4)0.f, axo = (floatx4)0.f;
        if (l0) {
#pragma unroll
            for (int kk = 0; kk < 4; ++kk) {
                MFMA16(ar, a0[kk], B0r[kk]);
                MFMA16(au, a0[kk], B0u[kk]);
            }
        }
        if (l1) {
#pragma unroll
            for (int kk = 0; kk < 4; ++kk) {
                MFMA16(a1r, a0[kk], Bxr[kk]);
                MFMA16(a1u, a0[kk], Bxu[kk]);
                MFMA16(axo, a0[kk], Bxo[kk]);
                MFMA16(a1r, a1[kk], B1r[kk]);
                MFMA16(a1u, a1[kk], B1u[kk]);
            }
        }
        if (l0) {
            float rg = fast_sigmoid(ar[0] + xr + b0r_c);
            ug0s = fast_sigmoid(au[0] + xu + b0u_c);
            Rbf0[swi] = cvt_bf16(rg * h0s);
        }
        if (l1) {
            float rg1 = fast_sigmoid(a1r[0] + br1c);
            ug1s = fast_sigmoid(a1u[0] + bu1c);
            Rbf1[swi] = cvt_bf16(rg1 * h1s);
        }
        sync_lds();

        // ---- Phase B: both o gates + both h updates
        floatx4 ao = (floatx4)0.f;
        if (l0) {
#pragma unroll
            for (int kk = 0; kk < 4; ++kk)
                MFMA16(ao, ldsA_r4(Rbf0, l15, kk, quad), B0o[kk]);
        }
        if (l1) {
#pragma unroll
            for (int kk = 0; kk < 4; ++kk)
                MFMA16(axo, ldsA_r4(Rbf1, l15, kk, quad), B1o[kk]);
        }
        if (l0) {
            float og = fast_tanh(ao[0] + xo + b0o_c);
            h0s = h0s + ug0s * (og - h0s);
            Hbf0[swi] = cvt_bf16(h0s);
        }
        if (l1) {
            float og1 = fast_tanh(axo[0] + bo1c);
            h1s = h1s + ug1s * (og1 - h1s);
            Hbf1[swi] = cvt_bf16(h1s);
        }
        if (pf) { xr = nr; xu = nu; xo = no; }
        sync_lds();
    }

    // ---- CLS tail: out[b0+r][cc] = bfc[cc] + sum_k h1[r][k]*Wfc[k][cc]
    Hf[quad][c] = h1s;
    sync_lds();
    for (int cc = tid; cc < NCLS; cc += 512) {
        float a0a = bfc[cc], a1a = bfc[cc], a2a = bfc[cc], a3a = bfc[cc];
#pragma unroll 8
        for (int k = 0; k < HID; ++k) {
            const float wf = Wfc[(size_t)k * NCLS + cc];
            a0a = __builtin_fmaf(Hf[0][k], wf, a0a);
            a1a = __builtin_fmaf(Hf[1][k], wf, a1a);
            a2a = __builtin_fmaf(Hf[2][k], wf, a2a);
            a3a = __builtin_fmaf(Hf[3][k], wf, a3a);
        }
        float* ob = out + (size_t)b0 * NCLS + cc;
        ob[0]        = a0a;
        ob[NCLS]     = a1a;
        ob[2 * NCLS] = a2a;
        ob[3 * NCLS] = a3a;
    }
}

// ---------------------------------------------------------------------------
extern "C" void kernel_launch(void* const* d_in, const int* in_sizes, int n_in,
                              void* d_out, int out_size, void* d_ws, size_t ws_size,
                              hipStream_t stream)
{
    const float* X   = (const float*)d_in[0];
    const float* Wr0 = (const float*)d_in[1];
    const float* br0 = (const float*)d_in[2];
    const float* Wu0 = (const float*)d_in[3];
    const float* bu0 = (const float*)d_in[4];
    const float* Wo0 = (const float*)d_in[5];
    const float* bo0 = (const float*)d_in[6];
    const float* Wr1 = (const float*)d_in[7];
    const float* br1 = (const float*)d_in[8];
    const float* bu1 = (const float*)d_in[9];
    const float* bu1f = (const float*)d_in[10];
    const float* Wo1 = (const float*)d_in[11];
    const float* bo1 = (const float*)d_in[12];
    const float* Wfc = (const float*)d_in[13];
    const float* bfc = (const float*)d_in[14];
    // NOTE: keep the original, verified input unpacking (indices 7..12):
    const float* Wr1v = (const float*)d_in[7];
    const float* br1v = (const float*)d_in[8];
    const float* Wu1v = (const float*)d_in[9];
    const float* bu1v = (const float*)d_in[10];
    const float* Wo1v = (const float*)d_in[11];
    const float* bo1v = (const float*)d_in[12];
    (void)Wr1; (void)bu1; (void)bu1f;
    float* out = (float*)d_out;

    // workspace:
    //   XG  fp32 [64][281][4][384]  110,493,696 B  ([b>>2][t][b&3][chan])
    //   Abf bf16 [M_TOT*288]         41,435,136 B  ([t][b][k])
    //   Wt0 bf16 [3*128*288]            221,184 B
    //   Wh0/Wx1/Wh1 bf16 [384*128]       98,304 B each
    char* ws = (char*)d_ws;
    float*          XG    = (float*)ws;
    unsigned short* Abf   = (unsigned short*)(ws + (size_t)M_TOT * 384 * 4);
    unsigned short* Wt0   = (unsigned short*)(ws + (size_t)M_TOT * 384 * 4 + (size_t)M_TOT * KPAD0 * 2);
    unsigned short* Wh0   = Wt0 + (size_t)3 * HID * KPAD0;
    unsigned short* Wx1   = Wh0 + (size_t)384 * HID;
    unsigned short* Wh1   = Wx1 + (size_t)384 * HID;

    prep_kernel<<<dim3(1664), 256, 0, stream>>>(X, Wr0, Wu0, Wo0, Wr1v, Wu1v, Wo1v,
                                                Abf, Wt0, Wh0, Wx1, Wh1);
    gemm_xg  <<<dim3(M_TOT / 128, 3), 256, 0, stream>>>(Abf, Wt0, XG);
    gru_fused<<<dim3(64), 512, 0, stream>>>(Wh0, Wx1, Wh1, XG,
                                            br0, bu0, bo0, br1v, bu1v, bo1v,
                                            Wfc, bfc, out);
}

// Round 11
// 450.987 us; speedup vs baseline: 1.1250x; 1.0449x over previous
//
#include <hip/hip_runtime.h>
#include <math.h>

#define HID    128
#define IN_CH  271
#define SEQ    281
#define NCLS   1854
#define BATCH  256
#define M_TOT  (SEQ * BATCH)          // 71936 = 562 * 128
#define KPAD0  288                    // 271 padded to 9*32

typedef __attribute__((ext_vector_type(8))) short short8;
typedef __attribute__((ext_vector_type(4))) float floatx4;

#define MFMA16(acc, a, b) acc = __builtin_amdgcn_mfma_f32_16x16x32_bf16((a), (b), (acc), 0, 0, 0)

__device__ __forceinline__ unsigned short f2bf(float f) {
    union { float f; unsigned u; } v; v.f = f;
    unsigned u = v.u;
    u += 0x7FFF + ((u >> 16) & 1);        // RNE
    return (unsigned short)(u >> 16);
}
// single-instruction bf16 convert (RNE, bit-identical to f2bf for finite vals)
__device__ __forceinline__ unsigned short cvt_bf16(float f) {
    unsigned r;
    asm("v_cvt_pk_bf16_f32 %0, %1, %1" : "=v"(r) : "v"(f));
    return (unsigned short)r;
}
__device__ __forceinline__ float fast_rcp(float x) {
    float r;
    asm("v_rcp_f32 %0, %1" : "=v"(r) : "v"(x));
    return r;
}
__device__ __forceinline__ float fast_sigmoid(float s) {
    return fast_rcp(1.f + __expf(-s));
}
// tanh(x) = 2/(1+e^{-2x}) - 1 ; exp limits give exactly -1/+1, branch-free
__device__ __forceinline__ float fast_tanh(float s) {
    float e = __expf(-2.f * s);
    return __builtin_fmaf(2.f, fast_rcp(1.f + e), -1.f);
}
// LDS-only barrier: waits ds-ops but does NOT drain vmcnt.
__device__ __forceinline__ void sync_lds() {
    asm volatile("s_waitcnt lgkmcnt(0)\n\ts_barrier" ::: "memory");
}

// ---------------------------------------------------------------------------
// 4-row swizzled LDS h-tile (R2-verified: SQ_LDS_BANK_CONFLICT = 0):
//   element (row, k) at  row*128 + (((k>>3) ^ (2*row)) << 3) + (k&7)
// ---------------------------------------------------------------------------
__device__ __forceinline__ short8 ldsA_r4(const unsigned short* base, int l15, int kk, int quad) {
    const int row4  = l15 >> 2;
    const int chunk = (4 * kk + quad) ^ (row4 << 1);
    return *(const short8*)(base + row4 * 128 + (chunk << 3));
}
__device__ __forceinline__ int sw_idx4(int row, int c) {
    return row * 128 + ((((c >> 3) ^ (row << 1)) << 3) | (c & 7));
}

// ---------------------------------------------------------------------------
// PREP (wt + xt merged — R10-proven).
// blocks 0..383   : weight transpose+convert (bid/32 = blk 0..11, bid%32 = n-slice)
//   blk 0..2 : Wt0 [n][288]        = W0g[k][n], k<271, zero-padded (gemm B)
//   blk 3..5 : Wh0 [g*128+n][128]  = W0g[271+k][n]
//   blk 6..8 : Wx1 [g*128+n][128]  = W1g[k][n]
//   blk 9..11: Wh1 [g*128+n][128]  = W1g[128+k][n]
// blocks 384..1663: X transpose+convert -> Abf[(t*256+b)*288 + k] bf16
// ---------------------------------------------------------------------------
__global__ __launch_bounds__(256) void prep_kernel(
    const float* __restrict__ X,
    const float* __restrict__ Wr0, const float* __restrict__ Wu0, const float* __restrict__ Wo0,
    const float* __restrict__ Wr1, const float* __restrict__ Wu1, const float* __restrict__ Wo1,
    unsigned short* __restrict__ Abf,
    unsigned short* __restrict__ Wt0, unsigned short* __restrict__ Wh0,
    unsigned short* __restrict__ Wx1, unsigned short* __restrict__ Wh1)
{
    __shared__ float Xl[32][65];
    const int bid = blockIdx.x;
    const int tid = threadIdx.x;

    if (bid < 384) {
        const int blk  = bid >> 5;          // 0..11
        const int kind = blk / 3, g = blk % 3;
        const int n0   = (bid & 31) * 4;

        const float* __restrict__ W =
            (kind <= 1) ? ((g == 0) ? Wr0 : (g == 1) ? Wu0 : Wo0)
                        : ((g == 0) ? Wr1 : (g == 1) ? Wu1 : Wo1);

        if (kind == 0) {
            unsigned short* __restrict__ out = Wt0 + (size_t)g * HID * KPAD0;
            for (int n = n0; n < n0 + 4; ++n)
                for (int k = tid; k < KPAD0; k += 256) {
                    float v = (k < IN_CH) ? W[(size_t)k * HID + n] : 0.f;
                    out[(size_t)n * KPAD0 + k] = f2bf(v);
                }
        } else {
            const int rbase = (kind == 1) ? IN_CH : (kind == 2) ? 0 : HID;
            unsigned short* __restrict__ out =
                ((kind == 1) ? Wh0 : (kind == 2) ? Wx1 : Wh1) + (size_t)g * HID * HID;
            for (int n = n0; n < n0 + 4; ++n)
                for (int k = tid; k < HID; k += 256)
                    out[(size_t)n * HID + k] = f2bf(W[(size_t)(rbase + k) * HID + n]);
        }
    } else {
        const int u  = bid - 384;
        const int tb = u % 5, b = u / 5;
        const int t0 = tb * 64;
        const float* __restrict__ Xb = X + (size_t)b * (IN_CH * SEQ);

        for (int kc = 0; kc < KPAD0 / 32; ++kc) {
#pragma unroll
            for (int r = 0; r < 8; ++r) {
                int e = tid + 256 * r;
                int kk = e >> 6, tt = e & 63;
                int k = kc * 32 + kk, t = t0 + tt;
                Xl[kk][tt] = (k < IN_CH && t < SEQ) ? Xb[k * SEQ + t] : 0.f;
            }
            __syncthreads();
            {
                int tt = tid >> 2, part = tid & 3;
                int t = t0 + tt;
                if (t < SEQ) {
                    union { unsigned short s[8]; uint4 v; } uu;
#pragma unroll
                    for (int i = 0; i < 8; ++i) uu.s[i] = f2bf(Xl[part * 8 + i][tt]);
                    *(uint4*)(Abf + ((size_t)t * BATCH + b) * KPAD0 + kc * 32 + part * 8) = uu.v;
                }
            }
            __syncthreads();
        }
    }
}

// ---------------------------------------------------------------------------
// bf16 MFMA GEMM (layer-0 x-contributions only) — R9/R10 verbatim.
// Abf[m'][k] (m' = t*256+b): A-tile = contiguous 73.7 KB panel.
// Output layout [b>>2][t][b&3][chan] (gru's proven read pattern).
// ---------------------------------------------------------------------------
__global__ __launch_bounds__(256) void gemm_xg(
    const unsigned short* __restrict__ A,
    const unsigned short* __restrict__ Wt,
    float* __restrict__ XG)
{
    const int g = blockIdx.y;
    const unsigned short* __restrict__ B = Wt + (size_t)g * HID * KPAD0;

    __shared__ unsigned short As[128 * 40];
    __shared__ unsigned short Bs[128 * 40];

    const int tid   = threadIdx.x;
    const int lane  = tid & 63;
    const int wave  = tid >> 6;
    const int l15   = lane & 15;
    const int quad  = lane >> 4;
    const int mhalf = wave >> 1;
    const int nhalf = wave & 1;
    const int m0    = blockIdx.x * 128;
    const int tt    = m0 >> 8;
    const int b0m   = m0 & 255;

    floatx4 acc[4][4];
#pragma unroll
    for (int im = 0; im < 4; ++im)
#pragma unroll
        for (int in = 0; in < 4; ++in) acc[im][in] = (floatx4)0.f;

    const int r0 = tid >> 2, p0 = tid & 3;
    const int r1 = (tid + 256) >> 2, p1 = tid & 3;

    for (int kt = 0; kt < KPAD0 / 32; ++kt) {
        if (kt) __syncthreads();
        const int kb = kt * 32;
        uint4 va0 = *(const uint4*)(A + (size_t)(m0 + r0) * KPAD0 + kb + p0 * 8);
        uint4 va1 = *(const uint4*)(A + (size_t)(m0 + r1) * KPAD0 + kb + p1 * 8);
        uint4 vb0 = *(const uint4*)(B + (size_t)r0 * KPAD0 + kb + p0 * 8);
        uint4 vb1 = *(const uint4*)(B + (size_t)r1 * KPAD0 + kb + p1 * 8);
        *(uint4*)(As + r0 * 40 + p0 * 8) = va0;
        *(uint4*)(As + r1 * 40 + p1 * 8) = va1;
        *(uint4*)(Bs + r0 * 40 + p0 * 8) = vb0;
        *(uint4*)(Bs + r1 * 40 + p1 * 8) = vb1;
        __syncthreads();

        short8 af[4], bf[4];
#pragma unroll
        for (int im = 0; im < 4; ++im)
            af[im] = *(const short8*)(As + (mhalf * 64 + im * 16 + l15) * 40 + quad * 8);
#pragma unroll
        for (int in = 0; in < 4; ++in)
            bf[in] = *(const short8*)(Bs + (nhalf * 64 + in * 16 + l15) * 40 + quad * 8);
#pragma unroll
        for (int im = 0; im < 4; ++im)
#pragma unroll
            for (int in = 0; in < 4; ++in)
                MFMA16(acc[im][in], af[im], bf[in]);
    }

    // epilogue: XG[(bb>>2)][tt][j][g*128+n] = acc[im][in][j]  (raw, no bias)
#pragma unroll
    for (int im = 0; im < 4; ++im) {
        const int bb = b0m + mhalf * 64 + im * 16 + quad * 4;   // 4-aligned
        const size_t rbase = ((size_t)(bb >> 2) * SEQ + tt) * 1536;
#pragma unroll
        for (int in = 0; in < 4; ++in) {
            const int chan = g * HID + nhalf * 64 + in * 16 + l15;
            float* dst = XG + rbase + chan;
#pragma unroll
            for (int j = 0; j < 4; ++j)
                dst[j * 384] = acc[im][in][j];
        }
    }
}

// ---------------------------------------------------------------------------
// FUSED 2-layer GRU + CLASSIFIER TAIL — 64 blocks x 4 batch rows.
// Loop body = R7-R10-measured 250 us core (VGPR 116, conflicts 0), UNCHANGED.
// R11: tail restructured — R10's 4 sequential cc-passes (464 serial scalar
// loads, 2048 broadcast ds_reads, heavy 64-bit addr VALU -> +33 us) become
// ONE 128-k loop with 4 concurrent cc-streams: 16 accumulators, 4 loads/k
// (2 base ptrs + 2048B imm offsets), 4 shared Hf broadcasts/k, ~32 loads in
// flight.  fp32 floor ~1854 fma/thread (~2 us).  bfc-first init, k ascending
// -> bit-identical arithmetic to R10's tail.
// ---------------------------------------------------------------------------
__global__ __launch_bounds__(512, 1) void gru_fused(
    const unsigned short* __restrict__ Wh0,
    const unsigned short* __restrict__ Wx1,
    const unsigned short* __restrict__ Wh1,
    const float* __restrict__ XG,
    const float* __restrict__ br0, const float* __restrict__ bu0, const float* __restrict__ bo0,
    const float* __restrict__ br1, const float* __restrict__ bu1, const float* __restrict__ bo1,
    const float* __restrict__ Wfc, const float* __restrict__ bfc,
    float* __restrict__ out)
{
    const int b0   = blockIdx.x * 4;
    const int tid  = threadIdx.x;
    const int w    = tid >> 6;        // 0..7
    const int lane = tid & 63;
    const int l15  = lane & 15;
    const int quad = lane >> 4;       // this lane's batch row 0..3
    const int c    = w * 16 + l15;    // this lane's column 0..127

    __shared__ __attribute__((aligned(16))) unsigned short Hbf0[4 * 128];
    __shared__ __attribute__((aligned(16))) unsigned short Rbf0[4 * 128];
    __shared__ __attribute__((aligned(16))) unsigned short Hbf1[4 * 128];
    __shared__ __attribute__((aligned(16))) unsigned short Rbf1[4 * 128];
    __shared__ float Hf[4][HID];      // cls tail staging

    // hoisted weight B-fragments: 9 (layer,gate) tiles x 4 k-steps
    short8 B0r[4], B0u[4], B0o[4], Bxr[4], Bxu[4], Bxo[4], B1r[4], B1u[4], B1o[4];
#pragma unroll
    for (int kk = 0; kk < 4; ++kk) {
        const size_t off = (size_t)c * HID + kk * 32 + quad * 8;
        B0r[kk] = *(const short8*)(Wh0 + off);
        B0u[kk] = *(const short8*)(Wh0 + (size_t)128 * HID + off);
        B0o[kk] = *(const short8*)(Wh0 + (size_t)256 * HID + off);
        Bxr[kk] = *(const short8*)(Wx1 + off);
        Bxu[kk] = *(const short8*)(Wx1 + (size_t)128 * HID + off);
        Bxo[kk] = *(const short8*)(Wx1 + (size_t)256 * HID + off);
        B1r[kk] = *(const short8*)(Wh1 + off);
        B1u[kk] = *(const short8*)(Wh1 + (size_t)128 * HID + off);
        B1o[kk] = *(const short8*)(Wh1 + (size_t)256 * HID + off);
    }

    for (int idx = tid; idx < 4 * 128; idx += 512) {
        Hbf0[idx] = 0; Rbf0[idx] = 0; Hbf1[idx] = 0; Rbf1[idx] = 0;
    }

    float h0s = 0.f, h1s = 0.f, ug0s = 0.f, ug1s = 0.f;

    const float b0r_c = br0[c], b0u_c = bu0[c], b0o_c = bo0[c];
    const float br1c = br1[c], bu1c = bu1[c], bo1c = bo1[c];

    // swizzled write index for this lane's single cell (row=quad, col=c)
    const int swi = sw_idx4(quad, c);

    // XG [gb][t][r=quad][chan]: lane reads chan=c (+128,+256)
    const float* xgp = XG + (size_t)blockIdx.x * SEQ * 1536 + quad * 384 + c;
    float xr = xgp[0];
    float xu = xgp[128];
    float xo = xgp[256];
    xgp += 1536;
    __syncthreads();

    for (int i = 0; i <= SEQ; ++i) {
        const bool l0 = (i < SEQ);     // layer 0 computes step i
        const bool l1 = (i > 0);       // layer 1 computes step i-1

        // prefetch xg(i+1) — lands during this step's compute
        float nr, nu, no;
        const bool pf = (i + 1 < SEQ);
        if (pf) {
            nr = xgp[0];
            nu = xgp[128];
            no = xgp[256];
            xgp += 1536;
        }

        // ---- Phase A: single read of h0(i-1)/h1(i-2); all r,u gates + L1 o-x part
        short8 a0[4], a1[4];
#pragma unroll
        for (int kk = 0; kk < 4; ++kk) {
            a0[kk] = ldsA_r4(Hbf0, l15, kk, quad);
            a1[kk] = ldsA_r4(Hbf1, l15, kk, quad);
        }
        floatx4 ar = (floatx4)0.f, au = (floatx4)0.f;
        floatx4 a1r = (floatx4)0.f, a1u = (floatx4)0.f, axo = (floatx4)0.f;
        if (l0) {
#pragma unroll
            for (int kk = 0; kk < 4; ++kk) {
                MFMA16(ar, a0[kk], B0r[kk]);
                MFMA16(au, a0[kk], B0u[kk]);
            }
        }
        if (l1) {
#pragma unroll
            for (int kk = 0; kk < 4; ++kk) {
                MFMA16(a1r, a0[kk], Bxr[kk]);
                MFMA16(a1u, a0[kk], Bxu[kk]);
                MFMA16(axo, a0[kk], Bxo[kk]);
                MFMA16(a1r, a1[kk], B1r[kk]);
                MFMA16(a1u, a1[kk], B1u[kk]);
            }
        }
        if (l0) {
            float rg = fast_sigmoid(ar[0] + xr + b0r_c);
            ug0s = fast_sigmoid(au[0] + xu + b0u_c);
            Rbf0[swi] = cvt_bf16(rg * h0s);
        }
        if (l1) {
            float rg1 = fast_sigmoid(a1r[0] + br1c);
            ug1s = fast_sigmoid(a1u[0] + bu1c);
            Rbf1[swi] = cvt_bf16(rg1 * h1s);
        }
        sync_lds();

        // ---- Phase B: both o gates + both h updates
        floatx4 ao = (floatx4)0.f;
        if (l0) {
#pragma unroll
            for (int kk = 0; kk < 4; ++kk)
                MFMA16(ao, ldsA_r4(Rbf0, l15, kk, quad), B0o[kk]);
        }
        if (l1) {
#pragma unroll
            for (int kk = 0; kk < 4; ++kk)
                MFMA16(axo, ldsA_r4(Rbf1, l15, kk, quad), B1o[kk]);
        }
        if (l0) {
            float og = fast_tanh(ao[0] + xo + b0o_c);
            h0s = h0s + ug0s * (og - h0s);
            Hbf0[swi] = cvt_bf16(h0s);
        }
        if (l1) {
            float og1 = fast_tanh(axo[0] + bo1c);
            h1s = h1s + ug1s * (og1 - h1s);
            Hbf1[swi] = cvt_bf16(h1s);
        }
        if (pf) { xr = nr; xu = nu; xo = no; }
        sync_lds();
    }

    // ---- CLS tail (R11): one k-loop, 4 concurrent cc-streams
    //   out[b0+r][cc] = bfc[cc] + sum_k h1[r][k]*Wfc[k][cc],  cc = tid + s*512
    Hf[quad][c] = h1s;
    sync_lds();
    {
        const bool s3 = (tid + 1536) < NCLS;          // stream 3 partial (tid<318)
        float ac0[4], ac1[4], ac2[4], ac3[4];
        {
            const float bv0 = bfc[tid];
            const float bv1 = bfc[tid + 512];
            const float bv2 = bfc[tid + 1024];
            const float bv3 = s3 ? bfc[tid + 1536] : 0.f;
#pragma unroll
            for (int r = 0; r < 4; ++r) { ac0[r] = bv0; ac1[r] = bv1; ac2[r] = bv2; ac3[r] = bv3; }
        }
        const float* wp0 = Wfc + tid;                 // streams 0,1 at +0 / +512
        const float* wp1 = Wfc + tid + 1024;          // streams 2,3 at +0 / +512
#pragma unroll 8
        for (int k = 0; k < HID; ++k) {
            const float w0 = wp0[0];
            const float w1 = wp0[512];
            const float w2 = wp1[0];
            const float w3 = s3 ? wp1[512] : 0.f;
            const float h0v = Hf[0][k], h1v = Hf[1][k], h2v = Hf[2][k], h3v = Hf[3][k];
            ac0[0] = __builtin_fmaf(h0v, w0, ac0[0]);
            ac0[1] = __builtin_fmaf(h1v, w0, ac0[1]);
            ac0[2] = __builtin_fmaf(h2v, w0, ac0[2]);
            ac0[3] = __builtin_fmaf(h3v, w0, ac0[3]);
            ac1[0] = __builtin_fmaf(h0v, w1, ac1[0]);
            ac1[1] = __builtin_fmaf(h1v, w1, ac1[1]);
            ac1[2] = __builtin_fmaf(h2v, w1, ac1[2]);
            ac1[3] = __builtin_fmaf(h3v, w1, ac1[3]);
            ac2[0] = __builtin_fmaf(h0v, w2, ac2[0]);
            ac2[1] = __builtin_fmaf(h1v, w2, ac2[1]);
            ac2[2] = __builtin_fmaf(h2v, w2, ac2[2]);
            ac2[3] = __builtin_fmaf(h3v, w2, ac2[3]);
            ac3[0] = __builtin_fmaf(h0v, w3, ac3[0]);
            ac3[1] = __builtin_fmaf(h1v, w3, ac3[1]);
            ac3[2] = __builtin_fmaf(h2v, w3, ac3[2]);
            ac3[3] = __builtin_fmaf(h3v, w3, ac3[3]);
            wp0 += NCLS;
            wp1 += NCLS;
        }
        float* ob = out + (size_t)b0 * NCLS;
#pragma unroll
        for (int r = 0; r < 4; ++r) {
            ob[(size_t)r * NCLS + tid]        = ac0[r];
            ob[(size_t)r * NCLS + tid + 512]  = ac1[r];
            ob[(size_t)r * NCLS + tid + 1024] = ac2[r];
            if (s3) ob[(size_t)r * NCLS + tid + 1536] = ac3[r];
        }
    }
}

// ---------------------------------------------------------------------------
extern "C" void kernel_launch(void* const* d_in, const int* in_sizes, int n_in,
                              void* d_out, int out_size, void* d_ws, size_t ws_size,
                              hipStream_t stream)
{
    const float* X   = (const float*)d_in[0];
    const float* Wr0 = (const float*)d_in[1];
    const float* br0 = (const float*)d_in[2];
    const float* Wu0 = (const float*)d_in[3];
    const float* bu0 = (const float*)d_in[4];
    const float* Wo0 = (const float*)d_in[5];
    const float* bo0 = (const float*)d_in[6];
    const float* Wr1 = (const float*)d_in[7];
    const float* br1 = (const float*)d_in[8];
    const float* Wu1 = (const float*)d_in[9];
    const float* bu1 = (const float*)d_in[10];
    const float* Wo1 = (const float*)d_in[11];
    const float* bo1 = (const float*)d_in[12];
    const float* Wfc = (const float*)d_in[13];
    const float* bfc = (const float*)d_in[14];
    float* out = (float*)d_out;

    // workspace:
    //   XG  fp32 [64][281][4][384]  110,493,696 B  ([b>>2][t][b&3][chan])
    //   Abf bf16 [M_TOT*288]         41,435,136 B  ([t][b][k])
    //   Wt0 bf16 [3*128*288]            221,184 B
    //   Wh0/Wx1/Wh1 bf16 [384*128]       98,304 B each
    char* ws = (char*)d_ws;
    float*          XG    = (float*)ws;
    unsigned short* Abf   = (unsigned short*)(ws + (size_t)M_TOT * 384 * 4);
    unsigned short* Wt0   = (unsigned short*)(ws + (size_t)M_TOT * 384 * 4 + (size_t)M_TOT * KPAD0 * 2);
    unsigned short* Wh0   = Wt0 + (size_t)3 * HID * KPAD0;
    unsigned short* Wx1   = Wh0 + (size_t)384 * HID;
    unsigned short* Wh1   = Wx1 + (size_t)384 * HID;

    prep_kernel<<<dim3(1664), 256, 0, stream>>>(X, Wr0, Wu0, Wo0, Wr1, Wu1, Wo1,
                                                Abf, Wt0, Wh0, Wx1, Wh1);
    gemm_xg  <<<dim3(M_TOT / 128, 3), 256, 0, stream>>>(Abf, Wt0, XG);
    gru_fused<<<dim3(64), 512, 0, stream>>>(Wh0, Wx1, Wh1, XG,
                                            br0, bu0, bo0, br1, bu1, bo1,
                                            Wfc, bfc, out);
}

// Round 12
// 441.055 us; speedup vs baseline: 1.1504x; 1.0225x over previous
//
#include <hip/hip_runtime.h>
#include <math.h>

#define HID    128
#define IN_CH  271
#define SEQ    281
#define NCLS   1854
#define BATCH  256
#define M_TOT  (SEQ * BATCH)          // 71936 = 562 * 128
#define KPAD0  288                    // 271 padded to 9*32

typedef __attribute__((ext_vector_type(8))) short short8;
typedef __attribute__((ext_vector_type(4))) float floatx4;
typedef float f4u __attribute__((ext_vector_type(4), aligned(4)));   // 4B-aligned float4 (odd Wfc rows are 8B-aligned)

#define MFMA16(acc, a, b) acc = __builtin_amdgcn_mfma_f32_16x16x32_bf16((a), (b), (acc), 0, 0, 0)

__device__ __forceinline__ unsigned short f2bf(float f) {
    union { float f; unsigned u; } v; v.f = f;
    unsigned u = v.u;
    u += 0x7FFF + ((u >> 16) & 1);        // RNE
    return (unsigned short)(u >> 16);
}
// single-instruction bf16 convert (RNE, bit-identical to f2bf for finite vals)
__device__ __forceinline__ unsigned short cvt_bf16(float f) {
    unsigned r;
    asm("v_cvt_pk_bf16_f32 %0, %1, %1" : "=v"(r) : "v"(f));
    return (unsigned short)r;
}
__device__ __forceinline__ float fast_rcp(float x) {
    float r;
    asm("v_rcp_f32 %0, %1" : "=v"(r) : "v"(x));
    return r;
}
__device__ __forceinline__ float fast_sigmoid(float s) {
    return fast_rcp(1.f + __expf(-s));
}
// tanh(x) = 2/(1+e^{-2x}) - 1 ; exp limits give exactly -1/+1, branch-free
__device__ __forceinline__ float fast_tanh(float s) {
    float e = __expf(-2.f * s);
    return __builtin_fmaf(2.f, fast_rcp(1.f + e), -1.f);
}
// LDS-only barrier: waits ds-ops but does NOT drain vmcnt.
__device__ __forceinline__ void sync_lds() {
    asm volatile("s_waitcnt lgkmcnt(0)\n\ts_barrier" ::: "memory");
}

// ---------------------------------------------------------------------------
// 4-row swizzled LDS h-tile (R2-verified: SQ_LDS_BANK_CONFLICT = 0):
//   element (row, k) at  row*128 + (((k>>3) ^ (2*row)) << 3) + (k&7)
// ---------------------------------------------------------------------------
__device__ __forceinline__ short8 ldsA_r4(const unsigned short* base, int l15, int kk, int quad) {
    const int row4  = l15 >> 2;
    const int chunk = (4 * kk + quad) ^ (row4 << 1);
    return *(const short8*)(base + row4 * 128 + (chunk << 3));
}
__device__ __forceinline__ int sw_idx4(int row, int c) {
    return row * 128 + ((((c >> 3) ^ (row << 1)) << 3) | (c & 7));
}

// ---------------------------------------------------------------------------
// PREP (wt + xt merged — R10-proven).
// blocks 0..383   : weight transpose+convert (bid/32 = blk 0..11, bid%32 = n-slice)
//   blk 0..2 : Wt0 [n][288]        = W0g[k][n], k<271, zero-padded (gemm B)
//   blk 3..5 : Wh0 [g*128+n][128]  = W0g[271+k][n]
//   blk 6..8 : Wx1 [g*128+n][128]  = W1g[k][n]
//   blk 9..11: Wh1 [g*128+n][128]  = W1g[128+k][n]
// blocks 384..1663: X transpose+convert -> Abf[(t*256+b)*288 + k] bf16
// ---------------------------------------------------------------------------
__global__ __launch_bounds__(256) void prep_kernel(
    const float* __restrict__ X,
    const float* __restrict__ Wr0, const float* __restrict__ Wu0, const float* __restrict__ Wo0,
    const float* __restrict__ Wr1, const float* __restrict__ Wu1, const float* __restrict__ Wo1,
    unsigned short* __restrict__ Abf,
    unsigned short* __restrict__ Wt0, unsigned short* __restrict__ Wh0,
    unsigned short* __restrict__ Wx1, unsigned short* __restrict__ Wh1)
{
    __shared__ float Xl[32][65];
    const int bid = blockIdx.x;
    const int tid = threadIdx.x;

    if (bid < 384) {
        const int blk  = bid >> 5;          // 0..11
        const int kind = blk / 3, g = blk % 3;
        const int n0   = (bid & 31) * 4;

        const float* __restrict__ W =
            (kind <= 1) ? ((g == 0) ? Wr0 : (g == 1) ? Wu0 : Wo0)
                        : ((g == 0) ? Wr1 : (g == 1) ? Wu1 : Wo1);

        if (kind == 0) {
            unsigned short* __restrict__ out = Wt0 + (size_t)g * HID * KPAD0;
            for (int n = n0; n < n0 + 4; ++n)
                for (int k = tid; k < KPAD0; k += 256) {
                    float v = (k < IN_CH) ? W[(size_t)k * HID + n] : 0.f;
                    out[(size_t)n * KPAD0 + k] = f2bf(v);
                }
        } else {
            const int rbase = (kind == 1) ? IN_CH : (kind == 2) ? 0 : HID;
            unsigned short* __restrict__ out =
                ((kind == 1) ? Wh0 : (kind == 2) ? Wx1 : Wh1) + (size_t)g * HID * HID;
            for (int n = n0; n < n0 + 4; ++n)
                for (int k = tid; k < HID; k += 256)
                    out[(size_t)n * HID + k] = f2bf(W[(size_t)(rbase + k) * HID + n]);
        }
    } else {
        const int u  = bid - 384;
        const int tb = u % 5, b = u / 5;
        const int t0 = tb * 64;
        const float* __restrict__ Xb = X + (size_t)b * (IN_CH * SEQ);

        for (int kc = 0; kc < KPAD0 / 32; ++kc) {
#pragma unroll
            for (int r = 0; r < 8; ++r) {
                int e = tid + 256 * r;
                int kk = e >> 6, tt = e & 63;
                int k = kc * 32 + kk, t = t0 + tt;
                Xl[kk][tt] = (k < IN_CH && t < SEQ) ? Xb[k * SEQ + t] : 0.f;
            }
            __syncthreads();
            {
                int tt = tid >> 2, part = tid & 3;
                int t = t0 + tt;
                if (t < SEQ) {
                    union { unsigned short s[8]; uint4 v; } uu;
#pragma unroll
                    for (int i = 0; i < 8; ++i) uu.s[i] = f2bf(Xl[part * 8 + i][tt]);
                    *(uint4*)(Abf + ((size_t)t * BATCH + b) * KPAD0 + kc * 32 + part * 8) = uu.v;
                }
            }
            __syncthreads();
        }
    }
}

// ---------------------------------------------------------------------------
// bf16 MFMA GEMM (layer-0 x-contributions only) — R9/R10 verbatim.
// Abf[m'][k] (m' = t*256+b): A-tile = contiguous 73.7 KB panel.
// Output layout [b>>2][t][b&3][chan] (gru's proven read pattern).
// ---------------------------------------------------------------------------
__global__ __launch_bounds__(256) void gemm_xg(
    const unsigned short* __restrict__ A,
    const unsigned short* __restrict__ Wt,
    float* __restrict__ XG)
{
    const int g = blockIdx.y;
    const unsigned short* __restrict__ B = Wt + (size_t)g * HID * KPAD0;

    __shared__ unsigned short As[128 * 40];
    __shared__ unsigned short Bs[128 * 40];

    const int tid   = threadIdx.x;
    const int lane  = tid & 63;
    const int wave  = tid >> 6;
    const int l15   = lane & 15;
    const int quad  = lane >> 4;
    const int mhalf = wave >> 1;
    const int nhalf = wave & 1;
    const int m0    = blockIdx.x * 128;
    const int tt    = m0 >> 8;
    const int b0m   = m0 & 255;

    floatx4 acc[4][4];
#pragma unroll
    for (int im = 0; im < 4; ++im)
#pragma unroll
        for (int in = 0; in < 4; ++in) acc[im][in] = (floatx4)0.f;

    const int r0 = tid >> 2, p0 = tid & 3;
    const int r1 = (tid + 256) >> 2, p1 = tid & 3;

    for (int kt = 0; kt < KPAD0 / 32; ++kt) {
        if (kt) __syncthreads();
        const int kb = kt * 32;
        uint4 va0 = *(const uint4*)(A + (size_t)(m0 + r0) * KPAD0 + kb + p0 * 8);
        uint4 va1 = *(const uint4*)(A + (size_t)(m0 + r1) * KPAD0 + kb + p1 * 8);
        uint4 vb0 = *(const uint4*)(B + (size_t)r0 * KPAD0 + kb + p0 * 8);
        uint4 vb1 = *(const uint4*)(B + (size_t)r1 * KPAD0 + kb + p1 * 8);
        *(uint4*)(As + r0 * 40 + p0 * 8) = va0;
        *(uint4*)(As + r1 * 40 + p1 * 8) = va1;
        *(uint4*)(Bs + r0 * 40 + p0 * 8) = vb0;
        *(uint4*)(Bs + r1 * 40 + p1 * 8) = vb1;
        __syncthreads();

        short8 af[4], bf[4];
#pragma unroll
        for (int im = 0; im < 4; ++im)
            af[im] = *(const short8*)(As + (mhalf * 64 + im * 16 + l15) * 40 + quad * 8);
#pragma unroll
        for (int in = 0; in < 4; ++in)
            bf[in] = *(const short8*)(Bs + (nhalf * 64 + in * 16 + l15) * 40 + quad * 8);
#pragma unroll
        for (int im = 0; im < 4; ++im)
#pragma unroll
            for (int in = 0; in < 4; ++in)
                MFMA16(acc[im][in], af[im], bf[in]);
    }

    // epilogue: XG[(bb>>2)][tt][j][g*128+n] = acc[im][in][j]  (raw, no bias)
#pragma unroll
    for (int im = 0; im < 4; ++im) {
        const int bb = b0m + mhalf * 64 + im * 16 + quad * 4;   // 4-aligned
        const size_t rbase = ((size_t)(bb >> 2) * SEQ + tt) * 1536;
#pragma unroll
        for (int in = 0; in < 4; ++in) {
            const int chan = g * HID + nhalf * 64 + in * 16 + l15;
            float* dst = XG + rbase + chan;
#pragma unroll
            for (int j = 0; j < 4; ++j)
                dst[j * 384] = acc[im][in][j];
        }
    }
}

// ---------------------------------------------------------------------------
// FUSED 2-layer GRU + CLASSIFIER TAIL — 64 blocks x 4 batch rows.
// Loop body = R7-R11-measured 250 us core (VGPR 116, conflicts 0), UNCHANGED.
// R12 tail: R11's 4 scalar Wfc loads + 4 scalar Hf ds_reads per k (512 LDS
// instr/thread ~ 10 us LDS-pipe serialization) -> each thread owns 4
// CONSECUTIVE cc: ONE float4 Wfc load per k (1 KB/wave contiguous; aligned(4)
// vector type since odd k rows are 8B-aligned — global dwordx4 needs only
// 4B) and ds_read_b128 per row per 4-k chunk (128 LDS instr, b128@12cy).
// LDS ~5 us overlapping Wfc ~7 us stream.  bfc-init + ascending-k fma ->
// bit-identical per-cc arithmetic.  Boundary tid 463 (cc=1852, jmax=2)
// guarded at init/store; Wfc float4 in-bounds (max idx 235,513 < 237,312).
// ---------------------------------------------------------------------------
__global__ __launch_bounds__(512, 1) void gru_fused(
    const unsigned short* __restrict__ Wh0,
    const unsigned short* __restrict__ Wx1,
    const unsigned short* __restrict__ Wh1,
    const float* __restrict__ XG,
    const float* __restrict__ br0, const float* __restrict__ bu0, const float* __restrict__ bo0,
    const float* __restrict__ br1, const float* __restrict__ bu1, const float* __restrict__ bo1,
    const float* __restrict__ Wfc, const float* __restrict__ bfc,
    float* __restrict__ out)
{
    const int b0   = blockIdx.x * 4;
    const int tid  = threadIdx.x;
    const int w    = tid >> 6;        // 0..7
    const int lane = tid & 63;
    const int l15  = lane & 15;
    const int quad = lane >> 4;       // this lane's batch row 0..3
    const int c    = w * 16 + l15;    // this lane's column 0..127

    __shared__ __attribute__((aligned(16))) unsigned short Hbf0[4 * 128];
    __shared__ __attribute__((aligned(16))) unsigned short Rbf0[4 * 128];
    __shared__ __attribute__((aligned(16))) unsigned short Hbf1[4 * 128];
    __shared__ __attribute__((aligned(16))) unsigned short Rbf1[4 * 128];
    __shared__ __attribute__((aligned(16))) float Hf[4][HID];   // cls tail staging

    // hoisted weight B-fragments: 9 (layer,gate) tiles x 4 k-steps
    short8 B0r[4], B0u[4], B0o[4], Bxr[4], Bxu[4], Bxo[4], B1r[4], B1u[4], B1o[4];
#pragma unroll
    for (int kk = 0; kk < 4; ++kk) {
        const size_t off = (size_t)c * HID + kk * 32 + quad * 8;
        B0r[kk] = *(const short8*)(Wh0 + off);
        B0u[kk] = *(const short8*)(Wh0 + (size_t)128 * HID + off);
        B0o[kk] = *(const short8*)(Wh0 + (size_t)256 * HID + off);
        Bxr[kk] = *(const short8*)(Wx1 + off);
        Bxu[kk] = *(const short8*)(Wx1 + (size_t)128 * HID + off);
        Bxo[kk] = *(const short8*)(Wx1 + (size_t)256 * HID + off);
        B1r[kk] = *(const short8*)(Wh1 + off);
        B1u[kk] = *(const short8*)(Wh1 + (size_t)128 * HID + off);
        B1o[kk] = *(const short8*)(Wh1 + (size_t)256 * HID + off);
    }

    for (int idx = tid; idx < 4 * 128; idx += 512) {
        Hbf0[idx] = 0; Rbf0[idx] = 0; Hbf1[idx] = 0; Rbf1[idx] = 0;
    }

    float h0s = 0.f, h1s = 0.f, ug0s = 0.f, ug1s = 0.f;

    const float b0r_c = br0[c], b0u_c = bu0[c], b0o_c = bo0[c];
    const float br1c = br1[c], bu1c = bu1[c], bo1c = bo1[c];

    // swizzled write index for this lane's single cell (row=quad, col=c)
    const int swi = sw_idx4(quad, c);

    // XG [gb][t][r=quad][chan]: lane reads chan=c (+128,+256)
    const float* xgp = XG + (size_t)blockIdx.x * SEQ * 1536 + quad * 384 + c;
    float xr = xgp[0];
    float xu = xgp[128];
    float xo = xgp[256];
    xgp += 1536;
    __syncthreads();

    for (int i = 0; i <= SEQ; ++i) {
        const bool l0 = (i < SEQ);     // layer 0 computes step i
        const bool l1 = (i > 0);       // layer 1 computes step i-1

        // prefetch xg(i+1) — lands during this step's compute
        float nr, nu, no;
        const bool pf = (i + 1 < SEQ);
        if (pf) {
            nr = xgp[0];
            nu = xgp[128];
            no = xgp[256];
            xgp += 1536;
        }

        // ---- Phase A: single read of h0(i-1)/h1(i-2); all r,u gates + L1 o-x part
        short8 a0[4], a1[4];
#pragma unroll
        for (int kk = 0; kk < 4; ++kk) {
            a0[kk] = ldsA_r4(Hbf0, l15, kk, quad);
            a1[kk] = ldsA_r4(Hbf1, l15, kk, quad);
        }
        floatx4 ar = (floatx4)0.f, au = (floatx4)0.f;
        floatx4 a1r = (floatx4)0.f, a1u = (floatx4)0.f, axo = (floatx4)0.f;
        if (l0) {
#pragma unroll
            for (int kk = 0; kk < 4; ++kk) {
                MFMA16(ar, a0[kk], B0r[kk]);
                MFMA16(au, a0[kk], B0u[kk]);
            }
        }
        if (l1) {
#pragma unroll
            for (int kk = 0; kk < 4; ++kk) {
                MFMA16(a1r, a0[kk], Bxr[kk]);
                MFMA16(a1u, a0[kk], Bxu[kk]);
                MFMA16(axo, a0[kk], Bxo[kk]);
                MFMA16(a1r, a1[kk], B1r[kk]);
                MFMA16(a1u, a1[kk], B1u[kk]);
            }
        }
        if (l0) {
            float rg = fast_sigmoid(ar[0] + xr + b0r_c);
            ug0s = fast_sigmoid(au[0] + xu + b0u_c);
            Rbf0[swi] = cvt_bf16(rg * h0s);
        }
        if (l1) {
            float rg1 = fast_sigmoid(a1r[0] + br1c);
            ug1s = fast_sigmoid(a1u[0] + bu1c);
            Rbf1[swi] = cvt_bf16(rg1 * h1s);
        }
        sync_lds();

        // ---- Phase B: both o gates + both h updates
        floatx4 ao = (floatx4)0.f;
        if (l0) {
#pragma unroll
            for (int kk = 0; kk < 4; ++kk)
                MFMA16(ao, ldsA_r4(Rbf0, l15, kk, quad), B0o[kk]);
        }
        if (l1) {
#pragma unroll
            for (int kk = 0; kk < 4; ++kk)
                MFMA16(axo, ldsA_r4(Rbf1, l15, kk, quad), B1o[kk]);
        }
        if (l0) {
            float og = fast_tanh(ao[0] + xo + b0o_c);
            h0s = h0s + ug0s * (og - h0s);
            Hbf0[swi] = cvt_bf16(h0s);
        }
        if (l1) {
            float og1 = fast_tanh(axo[0] + bo1c);
            h1s = h1s + ug1s * (og1 - h1s);
            Hbf1[swi] = cvt_bf16(h1s);
        }
        if (pf) { xr = nr; xu = nu; xo = no; }
        sync_lds();
    }

    // ---- CLS tail (R12): per-thread 4 consecutive cc; float4 Wfc, b128 Hf
    Hf[quad][c] = h1s;
    sync_lds();
    if (tid * 4 < NCLS) {
        const int cc   = tid * 4;
        const int jrem = NCLS - cc;
        const int jmax = (jrem >= 4) ? 4 : jrem;       // 4, or 2 for tid 463
        float ac[4][4];                                // [row r][j]
#pragma unroll
        for (int j = 0; j < 4; ++j) {
            const float bv = (j < jmax) ? bfc[cc + j] : 0.f;
#pragma unroll
            for (int r = 0; r < 4; ++r) ac[r][j] = bv;
        }
        const float* wp = Wfc + cc;
#pragma unroll 4
        for (int kc = 0; kc < HID; kc += 4) {
            floatx4 hv0 = *(const floatx4*)(&Hf[0][kc]);
            floatx4 hv1 = *(const floatx4*)(&Hf[1][kc]);
            floatx4 hv2 = *(const floatx4*)(&Hf[2][kc]);
            floatx4 hv3 = *(const floatx4*)(&Hf[3][kc]);
#pragma unroll
            for (int kk = 0; kk < 4; ++kk) {
                f4u wv = *(const f4u*)(wp);
                wp += NCLS;
#pragma unroll
                for (int j = 0; j < 4; ++j) {
                    ac[0][j] = __builtin_fmaf(hv0[kk], wv[j], ac[0][j]);
                    ac[1][j] = __builtin_fmaf(hv1[kk], wv[j], ac[1][j]);
                    ac[2][j] = __builtin_fmaf(hv2[kk], wv[j], ac[2][j]);
                    ac[3][j] = __builtin_fmaf(hv3[kk], wv[j], ac[3][j]);
                }
            }
        }
#pragma unroll
        for (int r = 0; r < 4; ++r) {
            float* ob = out + (size_t)(b0 + r) * NCLS + cc;
            if (jmax == 4) {
                *(f4u*)ob = *(const f4u*)&ac[r][0];
            } else {
                for (int j = 0; j < jmax; ++j) ob[j] = ac[r][j];
            }
        }
    }
}

// ---------------------------------------------------------------------------
extern "C" void kernel_launch(void* const* d_in, const int* in_sizes, int n_in,
                              void* d_out, int out_size, void* d_ws, size_t ws_size,
                              hipStream_t stream)
{
    const float* X   = (const float*)d_in[0];
    const float* Wr0 = (const float*)d_in[1];
    const float* br0 = (const float*)d_in[2];
    const float* Wu0 = (const float*)d_in[3];
    const float* bu0 = (const float*)d_in[4];
    const float* Wo0 = (const float*)d_in[5];
    const float* bo0 = (const float*)d_in[6];
    const float* Wr1 = (const float*)d_in[7];
    const float* br1 = (const float*)d_in[8];
    const float* Wu1 = (const float*)d_in[9];
    const float* bu1 = (const float*)d_in[10];
    const float* Wo1 = (const float*)d_in[11];
    const float* bo1 = (const float*)d_in[12];
    const float* Wfc = (const float*)d_in[13];
    const float* bfc = (const float*)d_in[14];
    float* out = (float*)d_out;

    // workspace:
    //   XG  fp32 [64][281][4][384]  110,493,696 B  ([b>>2][t][b&3][chan])
    //   Abf bf16 [M_TOT*288]         41,435,136 B  ([t][b][k])
    //   Wt0 bf16 [3*128*288]            221,184 B
    //   Wh0/Wx1/Wh1 bf16 [384*128]       98,304 B each
    char* ws = (char*)d_ws;
    float*          XG    = (float*)ws;
    unsigned short* Abf   = (unsigned short*)(ws + (size_t)M_TOT * 384 * 4);
    unsigned short* Wt0   = (unsigned short*)(ws + (size_t)M_TOT * 384 * 4 + (size_t)M_TOT * KPAD0 * 2);
    unsigned short* Wh0   = Wt0 + (size_t)3 * HID * KPAD0;
    unsigned short* Wx1   = Wh0 + (size_t)384 * HID;
    unsigned short* Wh1   = Wx1 + (size_t)384 * HID;

    prep_kernel<<<dim3(1664), 256, 0, stream>>>(X, Wr0, Wu0, Wo0, Wr1, Wu1, Wo1,
                                                Abf, Wt0, Wh0, Wx1, Wh1);
    gemm_xg  <<<dim3(M_TOT / 128, 3), 256, 0, stream>>>(Abf, Wt0, XG);
    gru_fused<<<dim3(64), 512, 0, stream>>>(Wh0, Wx1, Wh1, XG,
                                            br0, bu0, bo0, br1, bu1, bo1,
                                            Wfc, bfc, out);
}